// Round 2
// baseline (5252.618 us; speedup 1.0000x reference)
//
#include <hip/hip_runtime.h>
#include <hip/hip_bf16.h>
#include <stdint.h>

// GRU fused scan: B=128, T=512, I=H=512.
// 256 wgs x 192 threads (3 waves = gates r,z,n). wg (bgrp = id&7, ugrp = id>>3)
// owns batch rows [bgrp*16,+16) and hidden units [ugrp*16,+16).
// Weights live in VGPRs as bf16 MFMA B-fragments. h double-buffered in d_ws,
// exchanged via agent-scope atomics; per-step arrival counter per batch-group.
// Plain launch (not cooperative): 256 blocks, __launch_bounds__(192,2) ensures
// >=2 blocks/CU can be resident so all 256 are co-resident on 256 CUs.

static constexpr int INPUT = 512;
static constexpr int HID   = 512;
static constexpr int NB    = 128;
static constexpr int TLEN  = 512;
static constexpr int BGRPS = 8;
static constexpr int UGRPS = 32;

typedef __attribute__((ext_vector_type(4))) float f32x4;
typedef __attribute__((ext_vector_type(8))) short s16x8;

static __device__ __forceinline__ unsigned short f2bf(float f) {
  unsigned u = __builtin_bit_cast(unsigned, f);
  u += 0x7FFFu + ((u >> 16) & 1u);   // RNE
  return (unsigned short)(u >> 16);
}

// load 8 consecutive fp32 and convert to bf16x8 (A/B fragment payload)
static __device__ __forceinline__ s16x8 cvt8(const float* p) {
  f32x4 a = *(const f32x4*)p;
  f32x4 b = *(const f32x4*)(p + 4);
  s16x8 r;
  r[0] = (short)f2bf(a[0]); r[1] = (short)f2bf(a[1]);
  r[2] = (short)f2bf(a[2]); r[3] = (short)f2bf(a[3]);
  r[4] = (short)f2bf(b[0]); r[5] = (short)f2bf(b[1]);
  r[6] = (short)f2bf(b[2]); r[7] = (short)f2bf(b[3]);
  return r;
}

__global__ __launch_bounds__(192, 2) void gru_fused(
    const float* __restrict__ xs, const float* __restrict__ wih,
    const float* __restrict__ whh, const float* __restrict__ bias,
    const float* __restrict__ bias_n, float* __restrict__ out,
    unsigned short* __restrict__ hbuf, unsigned int* __restrict__ cnt)
{
  const int wg   = blockIdx.x;
  const int bgrp = wg & 7;
  const int ugrp = wg >> 3;
  const int b0   = bgrp * 16;
  const int u0   = ugrp * 16;
  const int tid  = threadIdx.x;
  const int g    = tid >> 6;      // 0=r, 1=z, 2=n
  const int lane = tid & 63;
  const int ln   = lane & 15;     // A-row (batch) / B-col (unit) index
  const int kg   = lane >> 4;     // k-octet group 0..3

  // ---- preload weight fragments into registers (one-time) ----
  const int rowW = g * HID + u0 + ln;      // row of [1536][512] weight matrices
  s16x8 wa[16], wb[16];
#pragma unroll
  for (int ks = 0; ks < 16; ++ks) {
    const int k = ks * 32 + kg * 8;
    wa[ks] = cvt8(wih + (size_t)rowW * INPUT + k);
    wb[ks] = cvt8(whh + (size_t)rowW * HID + k);
  }
  const float bv = bias[rowW];
  const float bn = bias_n[u0 + ln];

  const float* xrow = xs + (size_t)(b0 + ln) * TLEN * INPUT + kg * 8;
  const int hoff = (b0 + ln) * HID + kg * 8;   // bf16 element offset in one h buffer

  __shared__ float xch[4][16][16];   // [slot r/z/nx/nh][unit ln][batch row]

  float hold[4] = {0.f, 0.f, 0.f, 0.f};

  for (int t = 0; t < TLEN; ++t) {
    // ---- input-side GEMM for step t (independent of recurrence; hides wait) ----
    f32x4 acc_a = {bv, bv, bv, bv};
    const float* xp = xrow + (size_t)t * INPUT;
#pragma unroll
    for (int ks = 0; ks < 16; ++ks) {
      s16x8 xa = cvt8(xp + ks * 32);
      acc_a = __builtin_amdgcn_mfma_f32_16x16x32_bf16(xa, wa[ks], acc_a, 0, 0, 0);
    }

    // ---- wait until h[t] is fully published by this batch-group ----
    if (t > 0) {
      if (tid == 0) {
        while (__hip_atomic_load(&cnt[(t - 1) * BGRPS + bgrp],
                                 __ATOMIC_ACQUIRE, __HIP_MEMORY_SCOPE_AGENT) < (unsigned)UGRPS)
          __builtin_amdgcn_s_sleep(2);
      }
      __syncthreads();
      __builtin_amdgcn_sched_barrier(0);   // no compiler hoist of h loads above the wait
    }

    // ---- recurrent GEMM: hg = h[t] @ Whh^T  (h via coherent, cache-bypassing loads) ----
    const unsigned long long* hb =
        (const unsigned long long*)(hbuf + (size_t)(t & 1) * (NB * HID) + hoff);
    unsigned long long q0[16], q1[16];
#pragma unroll
    for (int ks = 0; ks < 16; ++ks) {
      q0[ks] = __hip_atomic_load(hb + ks * 8,     __ATOMIC_RELAXED, __HIP_MEMORY_SCOPE_AGENT);
      q1[ks] = __hip_atomic_load(hb + ks * 8 + 1, __ATOMIC_RELAXED, __HIP_MEMORY_SCOPE_AGENT);
    }
    f32x4 acc_b0 = {0.f, 0.f, 0.f, 0.f}, acc_b1 = {0.f, 0.f, 0.f, 0.f};
#pragma unroll
    for (int ks = 0; ks < 16; ks += 2) {
      union { unsigned long long q[2]; s16x8 s; } ua, ub;
      ua.q[0] = q0[ks];     ua.q[1] = q1[ks];
      ub.q[0] = q0[ks + 1]; ub.q[1] = q1[ks + 1];
      acc_b0 = __builtin_amdgcn_mfma_f32_16x16x32_bf16(ua.s, wb[ks],     acc_b0, 0, 0, 0);
      acc_b1 = __builtin_amdgcn_mfma_f32_16x16x32_bf16(ub.s, wb[ks + 1], acc_b1, 0, 0, 0);
    }
    f32x4 acc_b = acc_b0 + acc_b1;

    // ---- exchange gate pre-activations across the 3 waves ----
    if (g == 0)      { f32x4 s = acc_a + acc_b; *(f32x4*)&xch[0][ln][kg * 4] = s; }
    else if (g == 1) { f32x4 s = acc_a + acc_b; *(f32x4*)&xch[1][ln][kg * 4] = s; }
    else             { *(f32x4*)&xch[2][ln][kg * 4] = acc_a;
                       *(f32x4*)&xch[3][ln][kg * 4] = acc_b; }
    __syncthreads();
    f32x4 Sr  = *(const f32x4*)&xch[0][ln][kg * 4];
    f32x4 Sz  = *(const f32x4*)&xch[1][ln][kg * 4];
    f32x4 Snx = *(const f32x4*)&xch[2][ln][kg * 4];
    f32x4 Snh = *(const f32x4*)&xch[3][ln][kg * 4];

    // ---- gate math (all waves redundantly; keeps h_old in regs everywhere) ----
    float hnew[4];
#pragma unroll
    for (int i = 0; i < 4; ++i) {
      float r = 1.f / (1.f + __expf(-Sr[i]));
      float z = 1.f / (1.f + __expf(-Sz[i]));
      float pre = Snx[i] + r * (Snh[i] + bn);
      float e = __expf(2.f * pre);
      float n = 1.f - 2.f / (e + 1.f);   // tanh, overflow-safe
      hnew[i] = n + z * (hold[i] - n);
      hold[i] = hnew[i];
    }

    if (t == TLEN - 1) {
      if (g == 0) {
#pragma unroll
        for (int i = 0; i < 4; ++i)
          out[(size_t)(b0 + kg * 4 + i) * HID + u0 + ln] = hnew[i];
      }
    } else {
      // ---- publish h[t+1]: pack 4 adjacent units into one u64 coherent store ----
      if (g == 0) {
        unsigned short* hbn = hbuf + (size_t)((t + 1) & 1) * (NB * HID);
#pragma unroll
        for (int i = 0; i < 4; ++i) {
          int v  = (int)f2bf(hnew[i]);
          int o1 = __shfl_xor(v, 1);
          unsigned int p = (unsigned int)(v & 0xffff) | ((unsigned int)(o1 & 0xffff) << 16);
          unsigned int o2 = (unsigned int)__shfl_xor((int)p, 2);
          if ((ln & 3) == 0) {
            unsigned long long q = (unsigned long long)p | ((unsigned long long)o2 << 32);
            __hip_atomic_store(
                (unsigned long long*)(hbn + (size_t)(b0 + kg * 4 + i) * HID + u0 + ln),
                q, __ATOMIC_RELAXED, __HIP_MEMORY_SCOPE_AGENT);
          }
        }
      }
      __syncthreads();   // drains stores (vmcnt 0) + protects xch WAR
      if (tid == 0)
        __hip_atomic_fetch_add(&cnt[t * BGRPS + bgrp], 1u,
                               __ATOMIC_RELEASE, __HIP_MEMORY_SCOPE_AGENT);
    }
  }
}

extern "C" void kernel_launch(void* const* d_in, const int* in_sizes, int n_in,
                              void* d_out, int out_size, void* d_ws, size_t ws_size,
                              hipStream_t stream) {
  const float* xs     = (const float*)d_in[0];
  const float* wih    = (const float*)d_in[1];
  const float* whh    = (const float*)d_in[2];
  const float* bias   = (const float*)d_in[3];
  const float* bias_n = (const float*)d_in[4];
  float* out = (float*)d_out;

  const size_t hbuf_bytes = (size_t)2 * NB * HID * sizeof(unsigned short); // 256 KB
  const size_t cnt_bytes  = (size_t)TLEN * BGRPS * sizeof(unsigned int);   // 16 KB
  unsigned short* hbuf = (unsigned short*)d_ws;
  unsigned int*   cnt  = (unsigned int*)((char*)d_ws + hbuf_bytes);

  hipMemsetAsync(d_ws, 0, hbuf_bytes + cnt_bytes, stream);

  gru_fused<<<dim3(BGRPS * UGRPS), dim3(192), 0, stream>>>(
      xs, wih, whh, bias, bias_n, out, hbuf, cnt);
}

// Round 3
// 4168.551 us; speedup vs baseline: 1.2601x; 1.2601x over previous
//
#include <hip/hip_runtime.h>
#include <hip/hip_bf16.h>
#include <stdint.h>

// GRU fused scan: B=128, T=512, I=H=512.
// 256 wgs x 192 threads (3 waves = gates r,z,n). wg (bgrp = id&7, ugrp = id>>3)
// owns batch rows [bgrp*16,+16) and hidden units [ugrp*16,+16).
// Weights live in VGPRs as bf16 MFMA B-fragments. h double-buffered in d_ws,
// exchanged via agent-scope (IF-point) relaxed atomics. Sync per (step,bgrp):
// relaxed fetch_add arrival counter; producers order h-stores before the flag
// with s_waitcnt vmcnt(0); consumers order h-loads after the flag with
// control-dep + sched_barrier. NO acquire/release -> no per-step L1/L2
// invalidate/writeback on the critical path.
// x-side GEMM for step t+1 is computed AFTER publishing h[t+1], hiding it
// under cross-XCD flag propagation.

static constexpr int INPUT = 512;
static constexpr int HID   = 512;
static constexpr int NB    = 128;
static constexpr int TLEN  = 512;
static constexpr int BGRPS = 8;
static constexpr int UGRPS = 32;

typedef __attribute__((ext_vector_type(4))) float f32x4;
typedef __attribute__((ext_vector_type(8))) short s16x8;

static __device__ __forceinline__ unsigned short f2bf(float f) {
  unsigned u = __builtin_bit_cast(unsigned, f);
  u += 0x7FFFu + ((u >> 16) & 1u);   // RNE
  return (unsigned short)(u >> 16);
}

static __device__ __forceinline__ s16x8 cvt8(const float* p) {
  f32x4 a = *(const f32x4*)p;
  f32x4 b = *(const f32x4*)(p + 4);
  s16x8 r;
  r[0] = (short)f2bf(a[0]); r[1] = (short)f2bf(a[1]);
  r[2] = (short)f2bf(a[2]); r[3] = (short)f2bf(a[3]);
  r[4] = (short)f2bf(b[0]); r[5] = (short)f2bf(b[1]);
  r[6] = (short)f2bf(b[2]); r[7] = (short)f2bf(b[3]);
  return r;
}

__global__ __launch_bounds__(192, 2) void gru_fused(
    const float* __restrict__ xs, const float* __restrict__ wih,
    const float* __restrict__ whh, const float* __restrict__ bias,
    const float* __restrict__ bias_n, float* __restrict__ out,
    unsigned short* __restrict__ hbuf, unsigned int* __restrict__ cnt)
{
  const int wg   = blockIdx.x;
  const int bgrp = wg & 7;
  const int ugrp = wg >> 3;
  const int b0   = bgrp * 16;
  const int u0   = ugrp * 16;
  const int tid  = threadIdx.x;
  const int g    = tid >> 6;      // 0=r, 1=z, 2=n
  const int lane = tid & 63;
  const int ln   = lane & 15;     // A-row (batch) / B-col (unit) index
  const int kg   = lane >> 4;     // k-octet group 0..3

  // ---- preload weight fragments into registers (one-time) ----
  const int rowW = g * HID + u0 + ln;      // row of [1536][512] weight matrices
  s16x8 wa[16], wb[16];
#pragma unroll
  for (int ks = 0; ks < 16; ++ks) {
    const int k = ks * 32 + kg * 8;
    wa[ks] = cvt8(wih + (size_t)rowW * INPUT + k);
    wb[ks] = cvt8(whh + (size_t)rowW * HID + k);
  }
  const float bv = bias[rowW];
  const float bn = bias_n[u0 + ln];

  const float* xrow = xs + (size_t)(b0 + ln) * TLEN * INPUT + kg * 8;
  const int hoff = (b0 + ln) * HID + kg * 8;   // bf16 element offset in one h buffer

  __shared__ float xch[4][16][16];   // [slot r/z/nx/nh][unit ln][batch row]

  float hold[4] = {0.f, 0.f, 0.f, 0.f};

  // ---- prologue: input-side GEMM for t = 0 ----
  f32x4 acc_a = {bv, bv, bv, bv};
#pragma unroll
  for (int ks = 0; ks < 16; ++ks) {
    s16x8 xa = cvt8(xrow + ks * 32);
    acc_a = __builtin_amdgcn_mfma_f32_16x16x32_bf16(xa, wa[ks], acc_a, 0, 0, 0);
  }

  for (int t = 0; t < TLEN; ++t) {
    // ---- wait until h[t] is fully published by this batch-group ----
    if (t > 0) {
      if (tid == 0) {
        while (__hip_atomic_load(&cnt[(t - 1) * BGRPS + bgrp],
                                 __ATOMIC_RELAXED, __HIP_MEMORY_SCOPE_AGENT) < (unsigned)UGRPS) {}
      }
      __syncthreads();
      __builtin_amdgcn_sched_barrier(0);   // no hoist of h loads above the wait
    }

    // ---- recurrent GEMM: hg = h[t] @ Whh^T (h read at coherence point) ----
    const unsigned long long* hb =
        (const unsigned long long*)(hbuf + (size_t)(t & 1) * (NB * HID) + hoff);
    unsigned long long q0[16], q1[16];
#pragma unroll
    for (int ks = 0; ks < 16; ++ks) {
      q0[ks] = __hip_atomic_load(hb + ks * 8,     __ATOMIC_RELAXED, __HIP_MEMORY_SCOPE_AGENT);
      q1[ks] = __hip_atomic_load(hb + ks * 8 + 1, __ATOMIC_RELAXED, __HIP_MEMORY_SCOPE_AGENT);
    }
    f32x4 acc_b0 = {0.f, 0.f, 0.f, 0.f}, acc_b1 = {0.f, 0.f, 0.f, 0.f};
#pragma unroll
    for (int ks = 0; ks < 16; ks += 2) {
      union { unsigned long long q[2]; s16x8 s; } ua, ub;
      ua.q[0] = q0[ks];     ua.q[1] = q1[ks];
      ub.q[0] = q0[ks + 1]; ub.q[1] = q1[ks + 1];
      acc_b0 = __builtin_amdgcn_mfma_f32_16x16x32_bf16(ua.s, wb[ks],     acc_b0, 0, 0, 0);
      acc_b1 = __builtin_amdgcn_mfma_f32_16x16x32_bf16(ub.s, wb[ks + 1], acc_b1, 0, 0, 0);
    }
    f32x4 acc_b = acc_b0 + acc_b1;

    // ---- exchange gate pre-activations across the 3 waves ----
    if (g == 0)      { f32x4 s = acc_a + acc_b; *(f32x4*)&xch[0][ln][kg * 4] = s; }
    else if (g == 1) { f32x4 s = acc_a + acc_b; *(f32x4*)&xch[1][ln][kg * 4] = s; }
    else             { *(f32x4*)&xch[2][ln][kg * 4] = acc_a;
                       *(f32x4*)&xch[3][ln][kg * 4] = acc_b; }
    __syncthreads();
    f32x4 Sr  = *(const f32x4*)&xch[0][ln][kg * 4];
    f32x4 Sz  = *(const f32x4*)&xch[1][ln][kg * 4];
    f32x4 Snx = *(const f32x4*)&xch[2][ln][kg * 4];
    f32x4 Snh = *(const f32x4*)&xch[3][ln][kg * 4];

    // ---- gate math (all waves redundantly; keeps h_old in regs everywhere) ----
    float hnew[4];
#pragma unroll
    for (int i = 0; i < 4; ++i) {
      float r = 1.f / (1.f + __expf(-Sr[i]));
      float z = 1.f / (1.f + __expf(-Sz[i]));
      float pre = Snx[i] + r * (Snh[i] + bn);
      float e = __expf(2.f * pre);
      float n = 1.f - 2.f / (e + 1.f);   // tanh, overflow-safe
      hnew[i] = n + z * (hold[i] - n);
      hold[i] = hnew[i];
    }

    if (t == TLEN - 1) {
      if (g == 0) {
#pragma unroll
        for (int i = 0; i < 4; ++i)
          out[(size_t)(b0 + kg * 4 + i) * HID + u0 + ln] = hnew[i];
      }
    } else {
      // ---- publish h[t+1] FIRST (so propagation overlaps next x-GEMM) ----
      if (g == 0) {
        unsigned short* hbn = hbuf + (size_t)((t + 1) & 1) * (NB * HID);
#pragma unroll
        for (int i = 0; i < 4; ++i) {
          int v  = (int)f2bf(hnew[i]);
          int o1 = __shfl_xor(v, 1);
          unsigned int p = (unsigned int)(v & 0xffff) | ((unsigned int)(o1 & 0xffff) << 16);
          unsigned int o2 = (unsigned int)__shfl_xor((int)p, 2);
          if ((ln & 3) == 0) {
            unsigned long long q = (unsigned long long)p | ((unsigned long long)o2 << 32);
            __hip_atomic_store(
                (unsigned long long*)(hbn + (size_t)(b0 + kg * 4 + i) * HID + u0 + ln),
                q, __ATOMIC_RELAXED, __HIP_MEMORY_SCOPE_AGENT);
          }
        }
        asm volatile("s_waitcnt vmcnt(0)" ::: "memory");  // h stores acked at IF
        if (tid == 0)
          __hip_atomic_fetch_add(&cnt[t * BGRPS + bgrp], 1u,
                                 __ATOMIC_RELAXED, __HIP_MEMORY_SCOPE_AGENT);
      }

      // ---- input-side GEMM for step t+1 (hidden under flag propagation) ----
      acc_a = (f32x4){bv, bv, bv, bv};
      const float* xp = xrow + (size_t)(t + 1) * INPUT;
#pragma unroll
      for (int ks = 0; ks < 16; ++ks) {
        s16x8 xa = cvt8(xp + ks * 32);
        acc_a = __builtin_amdgcn_mfma_f32_16x16x32_bf16(xa, wa[ks], acc_a, 0, 0, 0);
      }
    }
  }
}

extern "C" void kernel_launch(void* const* d_in, const int* in_sizes, int n_in,
                              void* d_out, int out_size, void* d_ws, size_t ws_size,
                              hipStream_t stream) {
  const float* xs     = (const float*)d_in[0];
  const float* wih    = (const float*)d_in[1];
  const float* whh    = (const float*)d_in[2];
  const float* bias   = (const float*)d_in[3];
  const float* bias_n = (const float*)d_in[4];
  float* out = (float*)d_out;

  const size_t hbuf_bytes = (size_t)2 * NB * HID * sizeof(unsigned short); // 256 KB
  const size_t cnt_bytes  = (size_t)TLEN * BGRPS * sizeof(unsigned int);   // 16 KB
  unsigned short* hbuf = (unsigned short*)d_ws;
  unsigned int*   cnt  = (unsigned int*)((char*)d_ws + hbuf_bytes);

  hipMemsetAsync(d_ws, 0, hbuf_bytes + cnt_bytes, stream);

  gru_fused<<<dim3(BGRPS * UGRPS), dim3(192), 0, stream>>>(
      xs, wih, whh, bias, bias_n, out, hbuf, cnt);
}

// Round 6
// 3552.853 us; speedup vs baseline: 1.4784x; 1.1733x over previous
//
#include <hip/hip_runtime.h>
#include <hip/hip_bf16.h>
#include <stdint.h>

// GRU fused scan: B=128, T=512, I=H=512.
// 256 wgs x 192 threads (3 waves = gates r,z,n). wg (bgrp=id&7, ugrp=id>>3)
// owns batch rows [bgrp*16,+16) and hidden units [ugrp*16,+16).
// Weights live in registers as bf16 MFMA fragments. h double-buffered in d_ws
// (bf16), exchanged via agent-scope relaxed atomics (IF coherence point).
// Sync per (step,wg): ONE monotonic flag word per wg (flag[wg] = t+1, plain
// relaxed store after s_waitcnt vmcnt(0) drains the h stores). No RMW ->
// 32 producers publish in parallel. Consumers: all 64 lanes poll the 32 flags
// of their bgrp (lane&31) and exit on a full ballot -> wave-uniform control
// dependence orders the subsequent h loads; sched_barrier stops compiler
// hoisting. 1 KB of flags, 256 KB h double buffer: 257 KB of d_ws total
// (round-3 proved >= 272 KB is available).
// x-side GEMM for step t+1 runs AFTER publishing h[t+1] so flag/data
// propagation hides under it. One __syncthreads per step (dbuf LDS exchange).

static constexpr int INPUT = 512;
static constexpr int HID   = 512;
static constexpr int NB    = 128;
static constexpr int TLEN  = 512;
static constexpr int BGRPS = 8;
static constexpr int UGRPS = 32;

typedef __attribute__((ext_vector_type(4))) float f32x4;
typedef __attribute__((ext_vector_type(8))) short s16x8;

static __device__ __forceinline__ unsigned short f2bf(float f) {
  unsigned u = __builtin_bit_cast(unsigned, f);
  u += 0x7FFFu + ((u >> 16) & 1u);   // RNE
  return (unsigned short)(u >> 16);
}

static __device__ __forceinline__ s16x8 cvt8(const float* p) {
  f32x4 a = *(const f32x4*)p;
  f32x4 b = *(const f32x4*)(p + 4);
  s16x8 r;
  r[0] = (short)f2bf(a[0]); r[1] = (short)f2bf(a[1]);
  r[2] = (short)f2bf(a[2]); r[3] = (short)f2bf(a[3]);
  r[4] = (short)f2bf(b[0]); r[5] = (short)f2bf(b[1]);
  r[6] = (short)f2bf(b[2]); r[7] = (short)f2bf(b[3]);
  return r;
}

__global__ __launch_bounds__(192, 2) void gru_fused(
    const float* __restrict__ xs, const float* __restrict__ wih,
    const float* __restrict__ whh, const float* __restrict__ bias,
    const float* __restrict__ bias_n, float* __restrict__ out,
    unsigned short* __restrict__ hbuf, unsigned int* __restrict__ flags)
{
  const int wg   = blockIdx.x;
  const int bgrp = wg & 7;
  const int ugrp = wg >> 3;
  const int b0   = bgrp * 16;
  const int u0   = ugrp * 16;
  const int tid  = threadIdx.x;
  const int g    = tid >> 6;      // 0=r, 1=z, 2=n
  const int lane = tid & 63;
  const int ln   = lane & 15;     // unit / batch-row index within tile
  const int kg   = lane >> 4;     // k-octet group 0..3

  // ---- preload weight fragments into registers (one-time) ----
  const int rowW = g * HID + u0 + ln;      // row of [1536][512] weight matrices
  s16x8 wa[16], wb[16];
#pragma unroll
  for (int ks = 0; ks < 16; ++ks) {
    const int k = ks * 32 + kg * 8;
    wa[ks] = cvt8(wih + (size_t)rowW * INPUT + k);
    wb[ks] = cvt8(whh + (size_t)rowW * HID + k);
  }
  const float bv = bias[rowW];
  const float bn = bias_n[u0 + ln];

  const float* xrow = xs + (size_t)(b0 + ln) * TLEN * INPUT + kg * 8;
  const int hoff = (b0 + ln) * HID + kg * 8;   // ushort offset within one h slot

  __shared__ float xch[2][4][16][16];   // dbuf [slot r/z/nx/nh][unit][batch]

  float hold[4] = {0.f, 0.f, 0.f, 0.f};

  // ---- prologue: input-side GEMM for t = 0 ----
  f32x4 acc_a = {bv, bv, bv, bv};
#pragma unroll
  for (int ks = 0; ks < 16; ++ks) {
    s16x8 xa = cvt8(xrow + ks * 32);
    acc_a = __builtin_amdgcn_mfma_f32_16x16x32_bf16(xa, wa[ks], acc_a, 0, 0, 0);
  }

  for (int t = 0; t < TLEN; ++t) {
    // ---- wait: all 32 wgs of my bgrp have published h[t] (flag >= t) ----
    if (t > 0) {
      const unsigned* fp = &flags[bgrp * UGRPS + (lane & 31)];
      unsigned fv;
      do {
        fv = __hip_atomic_load(fp, __ATOMIC_RELAXED, __HIP_MEMORY_SCOPE_AGENT);
      } while (~__ballot(fv >= (unsigned)t));
      __builtin_amdgcn_sched_barrier(0);   // no hoist of h loads above the wait
    }

    // ---- load h[t] fragments (IF-point reads) ----
    const unsigned long long* hb =
        (const unsigned long long*)(hbuf + (size_t)(t & 1) * (NB * HID) + hoff);
    unsigned long long q0[16], q1[16];
#pragma unroll
    for (int ks = 0; ks < 16; ++ks) {
      q0[ks] = __hip_atomic_load(hb + ks * 8,     __ATOMIC_RELAXED, __HIP_MEMORY_SCOPE_AGENT);
      q1[ks] = __hip_atomic_load(hb + ks * 8 + 1, __ATOMIC_RELAXED, __HIP_MEMORY_SCOPE_AGENT);
    }

    // ---- recurrent GEMM: hg = h[t] @ Whh^T ----
    f32x4 acc_b0 = {0.f, 0.f, 0.f, 0.f}, acc_b1 = {0.f, 0.f, 0.f, 0.f};
#pragma unroll
    for (int ks = 0; ks < 16; ks += 2) {
      union { unsigned long long q[2]; s16x8 s; } ua, ub;
      ua.q[0] = q0[ks];     ua.q[1] = q1[ks];
      ub.q[0] = q0[ks + 1]; ub.q[1] = q1[ks + 1];
      acc_b0 = __builtin_amdgcn_mfma_f32_16x16x32_bf16(ua.s, wb[ks],     acc_b0, 0, 0, 0);
      acc_b1 = __builtin_amdgcn_mfma_f32_16x16x32_bf16(ub.s, wb[ks + 1], acc_b1, 0, 0, 0);
    }
    f32x4 acc_b = acc_b0 + acc_b1;

    // ---- exchange gate pre-activations across the 3 waves (dbuf LDS) ----
    float (*xc)[16][16] = xch[t & 1];
    if (g == 0)      { f32x4 s = acc_a + acc_b; *(f32x4*)&xc[0][ln][kg * 4] = s; }
    else if (g == 1) { f32x4 s = acc_a + acc_b; *(f32x4*)&xc[1][ln][kg * 4] = s; }
    else             { *(f32x4*)&xc[2][ln][kg * 4] = acc_a;
                       *(f32x4*)&xc[3][ln][kg * 4] = acc_b; }
    __syncthreads();
    f32x4 Sr  = *(const f32x4*)&xc[0][ln][kg * 4];
    f32x4 Sz  = *(const f32x4*)&xc[1][ln][kg * 4];
    f32x4 Snx = *(const f32x4*)&xc[2][ln][kg * 4];
    f32x4 Snh = *(const f32x4*)&xc[3][ln][kg * 4];

    // ---- gate math (all waves redundantly; keeps h_old in regs everywhere) ----
    float hnew[4];
#pragma unroll
    for (int i = 0; i < 4; ++i) {
      float r = 1.f / (1.f + __expf(-Sr[i]));
      float z = 1.f / (1.f + __expf(-Sz[i]));
      float pre = Snx[i] + r * (Snh[i] + bn);
      float e = __expf(2.f * pre);
      float n = 1.f - 2.f / (e + 1.f);   // tanh, overflow-safe
      hnew[i] = n + z * (hold[i] - n);
      hold[i] = hnew[i];
    }

    if (t == TLEN - 1) {
      if (g == 0) {
#pragma unroll
        for (int i = 0; i < 4; ++i)
          out[(size_t)(b0 + kg * 4 + i) * HID + u0 + ln] = hnew[i];
      }
    } else {
      // ---- publish h[t+1], drain, set flag = t+1; then x-GEMM t+1 ----
      if (g == 0) {
        unsigned short* hbn = hbuf + (size_t)((t + 1) & 1) * (NB * HID);
#pragma unroll
        for (int i = 0; i < 4; ++i) {
          int v  = (int)f2bf(hnew[i]);
          int o1 = __shfl_xor(v, 1);
          unsigned int p = (unsigned int)(v & 0xffff) | ((unsigned int)(o1 & 0xffff) << 16);
          unsigned int o2 = (unsigned int)__shfl_xor((int)p, 2);
          if ((ln & 3) == 0) {
            unsigned long long q = (unsigned long long)p | ((unsigned long long)o2 << 32);
            __hip_atomic_store(
                (unsigned long long*)(hbn + (size_t)(b0 + kg * 4 + i) * HID + u0 + ln),
                q, __ATOMIC_RELAXED, __HIP_MEMORY_SCOPE_AGENT);
          }
        }
        asm volatile("s_waitcnt vmcnt(0)" ::: "memory");  // h stores at IF
        if (tid == 0)
          __hip_atomic_store(&flags[bgrp * UGRPS + ugrp], (unsigned)(t + 1),
                             __ATOMIC_RELAXED, __HIP_MEMORY_SCOPE_AGENT);
      }

      // ---- input-side GEMM for step t+1 (hides flag/data propagation) ----
      acc_a = (f32x4){bv, bv, bv, bv};
      const float* xp = xrow + (size_t)(t + 1) * INPUT;
#pragma unroll
      for (int ks = 0; ks < 16; ++ks) {
        s16x8 xa = cvt8(xp + ks * 32);
        acc_a = __builtin_amdgcn_mfma_f32_16x16x32_bf16(xa, wa[ks], acc_a, 0, 0, 0);
      }
    }
  }
}

extern "C" void kernel_launch(void* const* d_in, const int* in_sizes, int n_in,
                              void* d_out, int out_size, void* d_ws, size_t ws_size,
                              hipStream_t stream) {
  const float* xs     = (const float*)d_in[0];
  const float* wih    = (const float*)d_in[1];
  const float* whh    = (const float*)d_in[2];
  const float* bias   = (const float*)d_in[3];
  const float* bias_n = (const float*)d_in[4];
  float* out = (float*)d_out;

  const size_t hbuf_bytes = (size_t)2 * NB * HID * sizeof(unsigned short); // 256 KB
  const size_t flg_bytes  = (size_t)BGRPS * UGRPS * sizeof(unsigned int);  // 1 KB
  unsigned short* hbuf  = (unsigned short*)d_ws;
  unsigned int*   flags = (unsigned int*)((char*)d_ws + hbuf_bytes);

  hipMemsetAsync(d_ws, 0, hbuf_bytes + flg_bytes, stream);

  gru_fused<<<dim3(BGRPS * UGRPS), dim3(192), 0, stream>>>(
      xs, wih, whh, bias, bias_n, out, hbuf, flags);
}